// Round 2
// baseline (43580.942 us; speedup 1.0000x reference)
//
#include <hip/hip_runtime.h>
#include <hip/hip_bf16.h>

typedef unsigned short u16;

#define LOGITS_N 25165824   // 262144 * 96

__device__ __forceinline__ float bf2f(u16 u) {
    return __uint_as_float(((unsigned int)u) << 16);
}
__device__ __forceinline__ u16 f2bf(float f) {
    unsigned int x = __float_as_uint(f);
    unsigned int r = (x + 0x7fffu + ((x >> 16) & 1u)) >> 16;
    return (u16)r;
}

// Dtype-agnostic float load: inputs are either f32 (expected) or bf16.
__device__ __forceinline__ float ldf(const void* p, int i, bool f32) {
    return f32 ? ((const float*)p)[i] : bf2f(((const u16*)p)[i]);
}

// One block per sequence. 256 threads = 4 waves. lane = token, wave = head / col-slice.
extern "C" __global__ void __launch_bounds__(256, 2)
slm_fwd(const int* __restrict__ g_idx, const int* __restrict__ g_tgt,
        const void* __restrict__ g_tok, const void* __restrict__ g_pos,
        const void* __restrict__ g_ln1g, const void* __restrict__ g_ln1b,
        const void* __restrict__ g_wq, const void* __restrict__ g_wk, const void* __restrict__ g_wv,
        const void* __restrict__ g_wo, const void* __restrict__ g_bo,
        const void* __restrict__ g_ln2g, const void* __restrict__ g_ln2b,
        const void* __restrict__ g_w1, const void* __restrict__ g_b1,
        const void* __restrict__ g_w2, const void* __restrict__ g_b2,
        const void* __restrict__ g_lnfg, const void* __restrict__ g_lnfb,
        const void* __restrict__ g_lmw, const void* __restrict__ g_lmb,
        float* __restrict__ g_out, float* g_loss)
{
    __shared__ __align__(16) u16   xs[64][68];   // bf16 residual stream
    __shared__ __align__(16) float hs[64][66];   // f32: LN output h, then attn output o
    __shared__ __align__(16) float r2[8704];     // 2 halves of 64*68 f32: weights / K,V / hidden
    __shared__ __align__(16) float red[3][4][64];

    const int tid  = threadIdx.x;
    const int wid  = tid >> 6;
    const int lane = tid & 63;
    const int b    = blockIdx.x;
    const int HALF = 64 * 68;   // 4352

    // dtype sniff: ln1_g[0] == 1.0. f32 word = 0x3F800000; packed bf16 pair = 0x3F803F80.
    const bool F32 = (((const unsigned int*)g_ln1g)[0] == 0x3F800000u);

    // ---------------- embedding ----------------
    for (int t = wid; t < 64; t += 4) {
        int tok = g_idx[b * 64 + t];
        float e = ldf(g_tok, tok * 64 + lane, F32) + ldf(g_pos, t * 64 + lane, F32);
        xs[t][lane] = f2bf(e);
    }
    __syncthreads();

    float hrow[64];

    auto loadrow = [&]() {
        #pragma unroll
        for (int i = 0; i < 32; ++i) {
            float2 v = *(const float2*)&hs[lane][2 * i];
            hrow[2 * i] = v.x; hrow[2 * i + 1] = v.y;
        }
    };

    // LayerNorm xs(bf16) -> hs(f32); 4 threads per token
    auto ln_phase = [&](const void* gp, const void* bp, int off) {
        int q4 = tid & 3, tk = tid >> 2;
        float xv[16]; float s1 = 0.f, s2 = 0.f;
        #pragma unroll
        for (int i = 0; i < 16; ++i) {
            float f = bf2f(xs[tk][q4 * 16 + i]);
            xv[i] = f; s1 += f; s2 += f * f;
        }
        s1 += __shfl_xor(s1, 1); s1 += __shfl_xor(s1, 2);
        s2 += __shfl_xor(s2, 1); s2 += __shfl_xor(s2, 2);
        float m   = s1 * 0.015625f;
        float var = s2 * 0.015625f - m * m;
        float rs  = rsqrtf(var + 1e-5f);
        #pragma unroll
        for (int i = 0; i < 16; ++i) {
            int c = q4 * 16 + i;
            hs[tk][c] = (xv[i] - m) * rs * ldf(gp, off + c, F32) + ldf(bp, off + c, F32);
        }
    };

    // out[16 cols] = hrow(64) dot W^T staged at wb ([j][c], stride 68); cols = wid*16..+15
    auto gemm16 = [&](const float* wb, float* acc) {
        #pragma unroll
        for (int s = 0; s < 16; ++s) acc[s] = 0.f;
        #pragma unroll
        for (int c4 = 0; c4 < 16; ++c4) {
            #pragma unroll
            for (int s = 0; s < 16; ++s) {
                float4 w4 = *(const float4*)&wb[(wid * 16 + s) * 68 + c4 * 4];
                acc[s] = fmaf(hrow[4 * c4 + 0], w4.x, acc[s]);
                acc[s] = fmaf(hrow[4 * c4 + 1], w4.y, acc[s]);
                acc[s] = fmaf(hrow[4 * c4 + 2], w4.z, acc[s]);
                acc[s] = fmaf(hrow[4 * c4 + 3], w4.w, acc[s]);
            }
        }
    };

    for (int l = 0; l < 4; ++l) {
        // ---------------- LN1 ----------------
        ln_phase(g_ln1g, g_ln1b, l * 64);
        __syncthreads();
        loadrow();                       // h row of my token into regs

        // ---------------- QKV (3 staged GEMMs) ----------------
        float qa[16], va[16];
        for (int m = 0; m < 3; ++m) {
            const void* wsrc = (m == 0 ? g_wq : (m == 1 ? g_wk : g_wv));
            for (int i = tid; i < 4096; i += 256) {     // stage W^T [j][c] into half0
                int j = i & 63, c = i >> 6;
                r2[j * 68 + c] = ldf(wsrc, l * 4096 + (j >> 4) * 1024 + c * 16 + (j & 15), F32);
            }
            __syncthreads();
            float acc[16];
            gemm16(r2, acc);
            if (m == 0) {
                #pragma unroll
                for (int s = 0; s < 16; ++s) qa[s] = acc[s];
            } else if (m == 1) {                        // K -> half1
                #pragma unroll
                for (int si = 0; si < 8; ++si)
                    *(float2*)&r2[HALF + lane * 68 + wid * 16 + 2 * si] =
                        make_float2(acc[2 * si], acc[2 * si + 1]);
            } else {
                #pragma unroll
                for (int s = 0; s < 16; ++s) va[s] = acc[s];
            }
            __syncthreads();
        }
        // V -> half0 (over staged wv)
        #pragma unroll
        for (int si = 0; si < 8; ++si)
            *(float2*)&r2[lane * 68 + wid * 16 + 2 * si] = make_float2(va[2 * si], va[2 * si + 1]);
        __syncthreads();

        // ---------------- attention: head = wid, my row = lane ----------------
        float sc[64];
        #pragma unroll
        for (int u = 0; u < 64; ++u) {
            const float* kr = &r2[HALF + u * 68 + wid * 16];
            float s = 0.f;
            #pragma unroll
            for (int i = 0; i < 4; ++i) {
                float4 k4 = *(const float4*)&kr[4 * i];
                s = fmaf(qa[4 * i + 0], k4.x, s);
                s = fmaf(qa[4 * i + 1], k4.y, s);
                s = fmaf(qa[4 * i + 2], k4.z, s);
                s = fmaf(qa[4 * i + 3], k4.w, s);
            }
            sc[u] = s * 0.25f;
        }
        float mx = -3.0e38f;
        #pragma unroll
        for (int u = 0; u < 64; ++u) mx = (u <= lane) ? fmaxf(mx, sc[u]) : mx;
        float den = 0.f, oa[16];
        #pragma unroll
        for (int s = 0; s < 16; ++s) oa[s] = 0.f;
        #pragma unroll
        for (int u = 0; u < 64; ++u) {
            float p = (u <= lane) ? __expf(sc[u] - mx) : 0.f;
            den += p;
            const float* vr = &r2[u * 68 + wid * 16];
            #pragma unroll
            for (int i = 0; i < 4; ++i) {
                float4 v4 = *(const float4*)&vr[4 * i];
                oa[4 * i + 0] = fmaf(p, v4.x, oa[4 * i + 0]);
                oa[4 * i + 1] = fmaf(p, v4.y, oa[4 * i + 1]);
                oa[4 * i + 2] = fmaf(p, v4.z, oa[4 * i + 2]);
                oa[4 * i + 3] = fmaf(p, v4.w, oa[4 * i + 3]);
            }
        }
        float inv = 1.0f / den;
        #pragma unroll
        for (int si = 0; si < 8; ++si)
            *(float2*)&hs[lane][wid * 16 + 2 * si] =
                make_float2(oa[2 * si] * inv, oa[2 * si + 1] * inv);   // o -> hs
        __syncthreads();

        // ---------------- output projection + residual ----------------
        for (int i = tid; i < 4096; i += 256) {         // stage wo^T [j][c]
            int j = i & 63, c = i >> 6;
            r2[j * 68 + c] = ldf(g_wo, l * 4096 + c * 64 + j, F32);
        }
        __syncthreads();
        loadrow();                                      // o row
        float pa[16];
        gemm16(r2, pa);
        #pragma unroll
        for (int s = 0; s < 16; ++s) {
            int j = wid * 16 + s;
            float xo = bf2f(xs[lane][j]);
            xs[lane][j] = f2bf(xo + pa[s] + ldf(g_bo, l * 64 + j, F32));
        }
        __syncthreads();

        // ---------------- LN2 + MLP ----------------
        ln_phase(g_ln2g, g_ln2b, l * 64);
        __syncthreads();
        loadrow();
        float outacc[16];
        #pragma unroll
        for (int s = 0; s < 16; ++s) outacc[s] = 0.f;
        for (int ch = 0; ch < 4; ++ch) {
            for (int i = tid; i < 4096; i += 256) {     // w1^T chunk -> half0
                int j = i & 63, c = i >> 6;
                r2[j * 68 + c] = ldf(g_w1, l * 16384 + c * 256 + ch * 64 + j, F32);
            }
            for (int i = tid; i < 4096; i += 256) {     // w2^T chunk [c][j] -> half1
                int c = i & 63, j = i >> 6;
                r2[HALF + c * 68 + j] = ldf(g_w2, l * 16384 + (ch * 64 + j) * 64 + c, F32);
            }
            __syncthreads();
            float hid[16];
            gemm16(r2, hid);                            // hidden slice (cols wid*16..)
            #pragma unroll
            for (int jj = 0; jj < 16; ++jj) {
                float bb = ldf(g_b1, l * 256 + ch * 64 + wid * 16 + jj, F32);
                hid[jj] = fmaxf(hid[jj] + bb, 0.f);
            }
            __syncthreads();
            #pragma unroll
            for (int si = 0; si < 8; ++si)              // hidden -> half0 (over w1t)
                *(float2*)&r2[lane * 68 + wid * 16 + 2 * si] =
                    make_float2(hid[2 * si], hid[2 * si + 1]);
            __syncthreads();
            #pragma unroll
            for (int j4 = 0; j4 < 16; ++j4) {           // out += hidden @ w2
                float4 h4 = *(const float4*)&r2[lane * 68 + 4 * j4];
                #pragma unroll
                for (int s = 0; s < 16; ++s) {
                    float4 w4 = *(const float4*)&r2[HALF + (wid * 16 + s) * 68 + 4 * j4];
                    outacc[s] = fmaf(h4.x, w4.x, outacc[s]);
                    outacc[s] = fmaf(h4.y, w4.y, outacc[s]);
                    outacc[s] = fmaf(h4.z, w4.z, outacc[s]);
                    outacc[s] = fmaf(h4.w, w4.w, outacc[s]);
                }
            }
            __syncthreads();
        }
        #pragma unroll
        for (int s = 0; s < 16; ++s) {
            int j = wid * 16 + s;
            float xo = bf2f(xs[lane][j]);
            xs[lane][j] = f2bf(xo + outacc[s] + ldf(g_b2, l * 64 + j, F32));
        }
        __syncthreads();
    }

    // ---------------- final LN + lm head + loss ----------------
    ln_phase(g_lnfg, g_lnfb, 0);
    __syncthreads();
    loadrow();
    for (int i = tid; i < 6144; i += 256) {             // lm_w^T [v][c]
        int v = i % 96, c = i / 96;
        r2[v * 68 + c] = ldf(g_lmw, c * 96 + v, F32);
    }
    __syncthreads();
    float la[24];
    #pragma unroll
    for (int vv = 0; vv < 24; ++vv) la[vv] = 0.f;
    #pragma unroll
    for (int c4 = 0; c4 < 16; ++c4) {
        #pragma unroll
        for (int vv = 0; vv < 24; ++vv) {
            float4 w4 = *(const float4*)&r2[(wid * 24 + vv) * 68 + 4 * c4];
            la[vv] = fmaf(hrow[4 * c4 + 0], w4.x, la[vv]);
            la[vv] = fmaf(hrow[4 * c4 + 1], w4.y, la[vv]);
            la[vv] = fmaf(hrow[4 * c4 + 2], w4.z, la[vv]);
            la[vv] = fmaf(hrow[4 * c4 + 3], w4.w, la[vv]);
        }
    }
    #pragma unroll
    for (int vv = 0; vv < 24; ++vv) la[vv] += ldf(g_lmb, wid * 24 + vv, F32);

    {
        size_t n = (size_t)b * 64 + lane;
        float* lp = g_out + n * 96 + wid * 24;
        #pragma unroll
        for (int vv = 0; vv < 24; ++vv) lp[vv] = la[vv];
    }

    float pm = -3.0e38f;
    #pragma unroll
    for (int vv = 0; vv < 24; ++vv) pm = fmaxf(pm, la[vv]);
    red[0][wid][lane] = pm;
    __syncthreads();
    float m4 = fmaxf(fmaxf(red[0][0][lane], red[0][1][lane]),
                     fmaxf(red[0][2][lane], red[0][3][lane]));
    float ps = 0.f;
    #pragma unroll
    for (int vv = 0; vv < 24; ++vv) ps += __expf(la[vv] - m4);
    red[1][wid][lane] = ps;
    int tgt = g_tgt[b * 64 + lane];
    if (tgt / 24 == wid) red[2][0][lane] = la[tgt - wid * 24];
    __syncthreads();
    if (wid == 0) {
        float den = red[1][0][lane] + red[1][1][lane] + red[1][2][lane] + red[1][3][lane];
        float lossv = -(red[2][0][lane] - m4 - logf(den));
        #pragma unroll
        for (int off = 32; off > 0; off >>= 1) lossv += __shfl_xor(lossv, off);
        if (lane == 0 && g_loss) atomicAdd(g_loss, lossv * (1.0f / 262144.0f));
    }
}

extern "C" void kernel_launch(void* const* d_in, const int* in_sizes, int n_in,
                              void* d_out, int out_size, void* d_ws, size_t ws_size,
                              hipStream_t stream) {
    (void)in_sizes; (void)n_in; (void)d_ws; (void)ws_size;
    float* out = (float*)d_out;
    float* loss_ptr = nullptr;
    if (out_size > LOGITS_N) {
        loss_ptr = out + LOGITS_N;
        hipMemsetAsync(loss_ptr, 0, sizeof(float) * (size_t)(out_size - LOGITS_N), stream);
    }
    slm_fwd<<<dim3(4096), dim3(256), 0, stream>>>(
        (const int*)d_in[0], (const int*)d_in[1],
        d_in[2], d_in[3],
        d_in[4], d_in[5],
        d_in[6], d_in[7], d_in[8],
        d_in[9], d_in[10],
        d_in[11], d_in[12],
        d_in[13], d_in[14],
        d_in[15], d_in[16],
        d_in[17], d_in[18],
        d_in[19], d_in[20],
        out, loss_ptr);
}

// Round 4
// 1388.518 us; speedup vs baseline: 31.3867x; 31.3867x over previous
//
#include <hip/hip_runtime.h>
#include <hip/hip_bf16.h>

typedef unsigned short u16;
typedef __attribute__((ext_vector_type(8))) short short8;
typedef __attribute__((ext_vector_type(4))) float f32x4;

#define LOGITS_N 25165824   // 262144 * 96

static __device__ __forceinline__ float bf2f(u16 u) {
    return __uint_as_float(((unsigned int)u) << 16);
}
static __device__ __forceinline__ u16 f2bf(float f) {
    unsigned int x = __float_as_uint(f);
    return (u16)((x + 0x7fffu + ((x >> 16) & 1u)) >> 16);
}
static __device__ __forceinline__ float ldf(const void* p, int i, bool f32) {
    return f32 ? ((const float*)p)[i] : bf2f(((const u16*)p)[i]);
}
static __device__ __forceinline__ float4 ldf4(const void* p, int i, bool f32) {
    if (f32) return *(const float4*)((const float*)p + i);
    const u16* q = (const u16*)p + i;
    return make_float4(bf2f(q[0]), bf2f(q[1]), bf2f(q[2]), bf2f(q[3]));
}
// swizzled element index within a 64-elem bf16 row: granule (c>>3) XOR'd by row&7
static __device__ __forceinline__ int swzi(int row, int c) {
    return (((c >> 3) ^ (row & 7)) << 3) | (c & 7);
}

// s_nop 1 prologue: VALU-write -> MFMA-read hazard guard (inline asm bypasses
// the compiler's hazard recognizer, so we insert the nops ourselves).
static __device__ __forceinline__ f32x4 mfma16(short8 a, short8 b, f32x4 c) {
    asm volatile("s_nop 1\n\tv_mfma_f32_16x16x32_bf16 %0, %1, %2, %0"
                 : "+v"(c) : "v"(a), "v"(b));
    return c;
}
// MFMA-write -> VALU-read guard: 3x s_nop 7 = 24 cycles, above worst-case XDL latency.
static __device__ __forceinline__ void fence4(f32x4* a) {
    asm volatile("s_nop 7\n\ts_nop 7\n\ts_nop 7"
                 : "+v"(a[0]), "+v"(a[1]), "+v"(a[2]), "+v"(a[3]));
}
static __device__ __forceinline__ void fence6(f32x4* a) {
    asm volatile("s_nop 7\n\ts_nop 7\n\ts_nop 7"
                 : "+v"(a[0]), "+v"(a[1]), "+v"(a[2]), "+v"(a[3]), "+v"(a[4]), "+v"(a[5]));
}

// Wave computes C[rbase..rbase+15][0..NT*16) over K=64.
// Ab: bf16 [Mrows][64] swizzled; Bb: bf16 [NT*16][64] swizzled (rows = output cols).
// Self-consistent k-slot packing: A and B use the SAME (hi,j)->column map, so the
// result is correct for ANY hardware k-slot bijection (only the m89-verified C/D
// layout is assumed: col=lane&15, row=(lane>>4)*4+reg).
template<int NT>
static __device__ __forceinline__ void gemm64(const u16* Ab, const u16* Bb,
                                              int lane, int rbase, f32x4* acc) {
    const int r15 = lane & 15, hi = lane >> 4;
    const int arow = rbase + r15;
    const short8 a0 = *(const short8*)(Ab + arow * 64 + (((0 + hi) ^ (arow & 7)) << 3));
    const short8 a1 = *(const short8*)(Ab + arow * 64 + (((4 + hi) ^ (arow & 7)) << 3));
    #pragma unroll
    for (int nt = 0; nt < NT; ++nt) {
        const int brow = nt * 16 + r15;
        const short8 b0 = *(const short8*)(Bb + brow * 64 + (((0 + hi) ^ (brow & 7)) << 3));
        const short8 b1 = *(const short8*)(Bb + brow * 64 + (((4 + hi) ^ (brow & 7)) << 3));
        acc[nt] = mfma16(a0, b0, acc[nt]);
        acc[nt] = mfma16(a1, b1, acc[nt]);
    }
}

// One block per sequence. 256 threads = 4 waves.
extern "C" __global__ void __launch_bounds__(256, 2)
slm_fwd(const int* __restrict__ g_idx, const int* __restrict__ g_tgt,
        const void* __restrict__ g_tok, const void* __restrict__ g_pos,
        const void* __restrict__ g_ln1g, const void* __restrict__ g_ln1b,
        const void* __restrict__ g_wq, const void* __restrict__ g_wk, const void* __restrict__ g_wv,
        const void* __restrict__ g_wo, const void* __restrict__ g_bo,
        const void* __restrict__ g_ln2g, const void* __restrict__ g_ln2b,
        const void* __restrict__ g_w1, const void* __restrict__ g_b1,
        const void* __restrict__ g_w2, const void* __restrict__ g_b2,
        const void* __restrict__ g_lnfg, const void* __restrict__ g_lnfb,
        const void* __restrict__ g_lmw, const void* __restrict__ g_lmb,
        float* __restrict__ g_out, float* g_loss)
{
    __shared__ __align__(16) u16 xs[64][68];    // residual, bf16
    __shared__ __align__(16) u16 hb[64 * 64];   // LN-out / attn-out, swizzled bf16 (A operand)
    __shared__ __align__(16) u16 wA[64 * 64];   // weight slot / K store
    __shared__ __align__(16) u16 wB[64 * 64];   // weight slot / V store
    __shared__ __align__(16) u16 wC[64 * 64];   // weight slot (wv / wo)
    __shared__ __align__(16) u16 qs[64 * 64];   // Q store / MLP hidden, swizzled
    __shared__ __align__(16) u16 lw[96 * 64];   // lm head weight, swizzled
    __shared__ float redl[16];

    const int tid  = threadIdx.x;
    const int wid  = tid >> 6;
    const int lane = tid & 63;
    const int hi   = lane >> 4;
    const int r15  = lane & 15;
    const int bIdx = blockIdx.x;
    const int rb   = wid * 16;                  // this wave's token-row base for GEMMs
    const f32x4 zero4 = {0.f, 0.f, 0.f, 0.f};

    // dtype sniff: ln1_g[0] == 1.0. f32 word = 0x3F800000; packed bf16 pair = 0x3F803F80.
    const bool F32 = (((const unsigned int*)g_ln1g)[0] == 0x3F800000u);

    // ---------------- embedding ----------------
    for (int t = wid; t < 64; t += 4) {
        int tok = g_idx[bIdx * 64 + t];
        float e = ldf(g_tok, tok * 64 + lane, F32) + ldf(g_pos, t * 64 + lane, F32);
        xs[t][lane] = f2bf(e);
    }
    __syncthreads();

    // LayerNorm xs(bf16) -> hb (swizzled bf16); 4 threads per token
    auto ln_phase = [&](const void* gp, const void* bp, int off) {
        int q4 = tid & 3, tk = tid >> 2;
        float xv[16]; float s1 = 0.f, s2 = 0.f;
        #pragma unroll
        for (int i = 0; i < 16; ++i) {
            float f = bf2f(xs[tk][q4 * 16 + i]);
            xv[i] = f; s1 += f; s2 += f * f;
        }
        s1 += __shfl_xor(s1, 1); s1 += __shfl_xor(s1, 2);
        s2 += __shfl_xor(s2, 1); s2 += __shfl_xor(s2, 2);
        float m  = s1 * 0.015625f;
        float rs = rsqrtf(s2 * 0.015625f - m * m + 1e-5f);
        unsigned w[8];
        #pragma unroll
        for (int i = 0; i < 16; i += 2) {
            int c0 = q4 * 16 + i;
            float y0 = (xv[i] - m) * rs * ldf(gp, off + c0, F32)     + ldf(bp, off + c0, F32);
            float y1 = (xv[i+1] - m) * rs * ldf(gp, off + c0 + 1, F32) + ldf(bp, off + c0 + 1, F32);
            w[i >> 1] = (unsigned)f2bf(y0) | ((unsigned)f2bf(y1) << 16);
        }
        int g0 = (2 * q4) ^ (tk & 7), g1 = (2 * q4 + 1) ^ (tk & 7);
        *(uint4*)&hb[tk * 64 + (g0 << 3)] = make_uint4(w[0], w[1], w[2], w[3]);
        *(uint4*)&hb[tk * 64 + (g1 << 3)] = make_uint4(w[4], w[5], w[6], w[7]);
    };

    for (int l = 0; l < 4; ++l) {
        // ---- LN1 -> hb ----
        ln_phase(g_ln1g, g_ln1b, l * 64);
        __syncthreads();                                    // B1

        // ---- stage wq^T->wA, wk^T->wB, wv^T->wC (swizzled bf16) ----
        for (int q = tid; q < 3072; q += 256) {
            int m = q >> 10, qq = q & 1023;
            int s4 = qq & 3, c = (qq >> 2) & 63, h = qq >> 8;
            const void* ws = (m == 0) ? g_wq : (m == 1) ? g_wk : g_wv;
            float4 w4 = ldf4(ws, l * 4096 + h * 1024 + c * 16 + s4 * 4, F32);
            u16* dst = (m == 0) ? wA : (m == 1) ? wB : wC;
            int nb = h * 16 + s4 * 4;
            dst[(nb + 0) * 64 + swzi(nb + 0, c)] = f2bf(w4.x);
            dst[(nb + 1) * 64 + swzi(nb + 1, c)] = f2bf(w4.y);
            dst[(nb + 2) * 64 + swzi(nb + 2, c)] = f2bf(w4.z);
            dst[(nb + 3) * 64 + swzi(nb + 3, c)] = f2bf(w4.w);
        }
        __syncthreads();                                    // B2

        // ---- QKV MFMA ----
        f32x4 aq[4], ak[4], av[4];
        #pragma unroll
        for (int nt = 0; nt < 4; ++nt) { aq[nt] = zero4; ak[nt] = zero4; av[nt] = zero4; }
        gemm64<4>(hb, wA, lane, rb, aq);
        gemm64<4>(hb, wB, lane, rb, ak);
        gemm64<4>(hb, wC, lane, rb, av);
        fence4(aq); fence4(ak); fence4(av);
        __syncthreads();                                    // B3 (all W/hb reads done)

        // ---- write Q->qs (swizzled), K->wA, V->wB (row-major); stage wo^T->wC ----
        #pragma unroll
        for (int nt = 0; nt < 4; ++nt)
            #pragma unroll
            for (int r = 0; r < 4; ++r) {
                int row = rb + hi * 4 + r, col = nt * 16 + r15;
                qs[row * 64 + swzi(row, col)] = f2bf(aq[nt][r]);
                wA[row * 64 + col] = f2bf(ak[nt][r]);
                wB[row * 64 + col] = f2bf(av[nt][r]);
            }
        for (int q = tid; q < 1024; q += 256) {
            int n4 = (q & 15) * 4, c = q >> 4;
            float4 w4 = ldf4(g_wo, l * 4096 + c * 64 + n4, F32);
            wC[(n4 + 0) * 64 + swzi(n4 + 0, c)] = f2bf(w4.x);
            wC[(n4 + 1) * 64 + swzi(n4 + 1, c)] = f2bf(w4.y);
            wC[(n4 + 2) * 64 + swzi(n4 + 2, c)] = f2bf(w4.z);
            wC[(n4 + 3) * 64 + swzi(n4 + 3, c)] = f2bf(w4.w);
        }
        __syncthreads();                                    // B4

        // ---- attention: lane = token, wid = head; K/V reads are wave-broadcast ----
        {
            const u16* qrow = qs + lane * 64;
            int ls = lane & 7;
            short8 q0 = *(const short8*)(qrow + ((((2 * wid)     ^ ls)) << 3));
            short8 q1 = *(const short8*)(qrow + ((((2 * wid + 1) ^ ls)) << 3));
            float qa[16];
            #pragma unroll
            for (int j = 0; j < 8; ++j) { qa[j] = bf2f((u16)q0[j]); qa[8 + j] = bf2f((u16)q1[j]); }
            float den = 0.f, oa[16];
            #pragma unroll
            for (int j = 0; j < 16; ++j) oa[j] = 0.f;
            for (int u = 0; u < 64; ++u) {
                const u16* kr = wA + u * 64 + wid * 16;
                short8 k0 = *(const short8*)kr, k1 = *(const short8*)(kr + 8);
                float s = 0.f;
                #pragma unroll
                for (int j = 0; j < 8; ++j) s = fmaf(qa[j], bf2f((u16)k0[j]), s);
                #pragma unroll
                for (int j = 0; j < 8; ++j) s = fmaf(qa[8 + j], bf2f((u16)k1[j]), s);
                float p = (u <= lane) ? __expf(fminf(s * 0.25f, 50.f)) : 0.f;
                den += p;
                const u16* vr = wB + u * 64 + wid * 16;
                short8 v0 = *(const short8*)vr, v1 = *(const short8*)(vr + 8);
                #pragma unroll
                for (int j = 0; j < 8; ++j) oa[j]     = fmaf(p, bf2f((u16)v0[j]), oa[j]);
                #pragma unroll
                for (int j = 0; j < 8; ++j) oa[8 + j] = fmaf(p, bf2f((u16)v1[j]), oa[8 + j]);
            }
            float inv = 1.f / den;
            unsigned w[8];
            #pragma unroll
            for (int i = 0; i < 16; i += 2)
                w[i >> 1] = (unsigned)f2bf(oa[i] * inv) | ((unsigned)f2bf(oa[i + 1] * inv) << 16);
            int g0 = (2 * wid) ^ ls, g1 = (2 * wid + 1) ^ ls;
            *(uint4*)&hb[lane * 64 + (g0 << 3)] = make_uint4(w[0], w[1], w[2], w[3]);
            *(uint4*)&hb[lane * 64 + (g1 << 3)] = make_uint4(w[4], w[5], w[6], w[7]);
        }
        __syncthreads();                                    // B5

        // ---- output projection + residual into xs ----
        {
            f32x4 ap[4];
            #pragma unroll
            for (int nt = 0; nt < 4; ++nt) ap[nt] = zero4;
            gemm64<4>(hb, wC, lane, rb, ap);
            fence4(ap);
            #pragma unroll
            for (int nt = 0; nt < 4; ++nt) {
                int col = nt * 16 + r15;
                float bb = ldf(g_bo, l * 64 + col, F32);
                #pragma unroll
                for (int r = 0; r < 4; ++r) {
                    int row = rb + hi * 4 + r;
                    xs[row][col] = f2bf(bf2f(xs[row][col]) + ap[nt][r] + bb);
                }
            }
        }
        __syncthreads();                                    // B6

        // ---- LN2 -> hb ----
        ln_phase(g_ln2g, g_ln2b, l * 64);
        __syncthreads();                                    // B7

        // ---- MLP: 4 chunks of 64 hidden, acc2 accumulates across chunks ----
        f32x4 acc2[4];
        #pragma unroll
        for (int nt = 0; nt < 4; ++nt) acc2[nt] = zero4;
        for (int ch = 0; ch < 4; ++ch) {
            for (int q = tid; q < 1024; q += 256) {         // w1^T chunk -> wA
                int j4 = (q & 15) * 4, c = q >> 4;
                float4 w4 = ldf4(g_w1, l * 16384 + c * 256 + ch * 64 + j4, F32);
                wA[(j4 + 0) * 64 + swzi(j4 + 0, c)] = f2bf(w4.x);
                wA[(j4 + 1) * 64 + swzi(j4 + 1, c)] = f2bf(w4.y);
                wA[(j4 + 2) * 64 + swzi(j4 + 2, c)] = f2bf(w4.z);
                wA[(j4 + 3) * 64 + swzi(j4 + 3, c)] = f2bf(w4.w);
            }
            for (int q = tid; q < 1024; q += 256) {         // w2^T chunk -> wB
                int n4 = (q & 15) * 4, jj = q >> 4;
                float4 w4 = ldf4(g_w2, l * 16384 + (ch * 64 + jj) * 64 + n4, F32);
                wB[(n4 + 0) * 64 + swzi(n4 + 0, jj)] = f2bf(w4.x);
                wB[(n4 + 1) * 64 + swzi(n4 + 1, jj)] = f2bf(w4.y);
                wB[(n4 + 2) * 64 + swzi(n4 + 2, jj)] = f2bf(w4.z);
                wB[(n4 + 3) * 64 + swzi(n4 + 3, jj)] = f2bf(w4.w);
            }
            __syncthreads();                                // B8
            f32x4 hacc[4];
            #pragma unroll
            for (int nt = 0; nt < 4; ++nt) hacc[nt] = zero4;
            gemm64<4>(hb, wA, lane, rb, hacc);
            fence4(hacc);
            #pragma unroll
            for (int nt = 0; nt < 4; ++nt) {
                int col = nt * 16 + r15;
                float bb = ldf(g_b1, l * 256 + ch * 64 + col, F32);
                #pragma unroll
                for (int r = 0; r < 4; ++r) {
                    int row = rb + hi * 4 + r;
                    float hv = fmaxf(hacc[nt][r] + bb, 0.f);
                    qs[row * 64 + swzi(row, col)] = f2bf(hv);
                }
            }
            __syncthreads();                                // B9
            gemm64<4>(qs, wB, lane, rb, acc2);
            __syncthreads();                                // B10
        }
        fence4(acc2);
        #pragma unroll
        for (int nt = 0; nt < 4; ++nt) {
            int col = nt * 16 + r15;
            float bb = ldf(g_b2, l * 64 + col, F32);
            #pragma unroll
            for (int r = 0; r < 4; ++r) {
                int row = rb + hi * 4 + r;
                xs[row][col] = f2bf(bf2f(xs[row][col]) + acc2[nt][r] + bb);
            }
        }
        __syncthreads();                                    // B11
    }

    // ---------------- final LN + lm head + loss ----------------
    ln_phase(g_lnfg, g_lnfb, 0);
    __syncthreads();
    for (int q = tid; q < 1536; q += 256) {                 // lm_w^T [v][c] -> lw
        int v4 = (q % 24) * 4, c = q / 24;
        float4 w4 = ldf4(g_lmw, c * 96 + v4, F32);
        lw[(v4 + 0) * 64 + swzi(v4 + 0, c)] = f2bf(w4.x);
        lw[(v4 + 1) * 64 + swzi(v4 + 1, c)] = f2bf(w4.y);
        lw[(v4 + 2) * 64 + swzi(v4 + 2, c)] = f2bf(w4.z);
        lw[(v4 + 3) * 64 + swzi(v4 + 3, c)] = f2bf(w4.w);
    }
    __syncthreads();

    f32x4 la[6];
    #pragma unroll
    for (int nt = 0; nt < 6; ++nt) la[nt] = zero4;
    gemm64<6>(hb, lw, lane, rb, la);
    fence6(la);
    #pragma unroll
    for (int nt = 0; nt < 6; ++nt) {
        float bb = ldf(g_lmb, nt * 16 + r15, F32);
        #pragma unroll
        for (int r = 0; r < 4; ++r) la[nt][r] += bb;
    }

    float lsum = 0.f;
    #pragma unroll
    for (int r = 0; r < 4; ++r) {
        int row = rb + hi * 4 + r;
        float mx = la[0][r];
        #pragma unroll
        for (int nt = 1; nt < 6; ++nt) mx = fmaxf(mx, la[nt][r]);
        mx = fmaxf(mx, __shfl_xor(mx, 1));
        mx = fmaxf(mx, __shfl_xor(mx, 2));
        mx = fmaxf(mx, __shfl_xor(mx, 4));
        mx = fmaxf(mx, __shfl_xor(mx, 8));
        float ps = 0.f;
        #pragma unroll
        for (int nt = 0; nt < 6; ++nt) ps += __expf(la[nt][r] - mx);
        ps += __shfl_xor(ps, 1); ps += __shfl_xor(ps, 2);
        ps += __shfl_xor(ps, 4); ps += __shfl_xor(ps, 8);
        size_t base = (size_t)(bIdx * 64 + row) * 96;
        #pragma unroll
        for (int nt = 0; nt < 6; ++nt) g_out[base + nt * 16 + r15] = la[nt][r];
        int tg = g_tgt[bIdx * 64 + row];
        float contrib = 0.f;
        #pragma unroll
        for (int nt = 0; nt < 6; ++nt)
            contrib += (((tg >> 4) == nt) && ((tg & 15) == r15)) ? la[nt][r] : 0.f;
        contrib += __shfl_xor(contrib, 1); contrib += __shfl_xor(contrib, 2);
        contrib += __shfl_xor(contrib, 4); contrib += __shfl_xor(contrib, 8);
        lsum += (mx + logf(ps) - contrib);
    }
    if (r15 == 0) redl[wid * 4 + hi] = lsum;
    __syncthreads();
    if (tid == 0 && g_loss) {
        float t = 0.f;
        #pragma unroll
        for (int i = 0; i < 16; ++i) t += redl[i];
        atomicAdd(g_loss, t * (1.0f / 262144.0f));
    }
}

extern "C" void kernel_launch(void* const* d_in, const int* in_sizes, int n_in,
                              void* d_out, int out_size, void* d_ws, size_t ws_size,
                              hipStream_t stream) {
    (void)in_sizes; (void)n_in; (void)d_ws; (void)ws_size;
    float* out = (float*)d_out;
    float* loss_ptr = nullptr;
    if (out_size > LOGITS_N) {
        loss_ptr = out + LOGITS_N;
        hipMemsetAsync(loss_ptr, 0, sizeof(float) * (size_t)(out_size - LOGITS_N), stream);
    }
    slm_fwd<<<dim3(4096), dim3(256), 0, stream>>>(
        (const int*)d_in[0], (const int*)d_in[1],
        d_in[2], d_in[3],
        d_in[4], d_in[5],
        d_in[6], d_in[7], d_in[8],
        d_in[9], d_in[10],
        d_in[11], d_in[12],
        d_in[13], d_in[14],
        d_in[15], d_in[16],
        d_in[17], d_in[18],
        d_in[19], d_in[20],
        out, loss_ptr);
}

// Round 5
// 758.344 us; speedup vs baseline: 57.4685x; 1.8310x over previous
//
#include <hip/hip_runtime.h>
#include <hip/hip_bf16.h>

typedef unsigned short u16;
typedef __attribute__((ext_vector_type(8))) short short8;
typedef __attribute__((ext_vector_type(4))) short short4b;
typedef __attribute__((ext_vector_type(4))) float f32x4;

#define LOGITS_N 25165824   // 262144 * 96

// ---- ws layout (u16 units): pre-swizzled bf16 LDS images ----
#define WS_WQ   0         // 4 layers x 4096
#define WS_WK   16384
#define WS_WV   32768
#define WS_WO   49152
#define WS_W1   65536     // (l*4+ch)*4096
#define WS_W2   131072
#define WS_LMW  196608    // 96x64 = 6144
#define WS_TOTAL_U16 202752

static __device__ __forceinline__ float bf2f(u16 u) {
    return __uint_as_float(((unsigned int)u) << 16);
}
static __device__ __forceinline__ u16 f2bf(float f) {
    unsigned int x = __float_as_uint(f);
    return (u16)((x + 0x7fffu + ((x >> 16) & 1u)) >> 16);
}
static __device__ __forceinline__ float ldf(const void* p, int i, bool f32) {
    return f32 ? ((const float*)p)[i] : bf2f(((const u16*)p)[i]);
}
static __device__ __forceinline__ float4 ldf4(const void* p, int i, bool f32) {
    if (f32) return *(const float4*)((const float*)p + i);
    const u16* q = (const u16*)p + i;
    return make_float4(bf2f(q[0]), bf2f(q[1]), bf2f(q[2]), bf2f(q[3]));
}
// 8-elem granule swizzle within a 64-elem bf16 row
static __device__ __forceinline__ int swzi(int row, int c) {
    return (((c >> 3) ^ (row & 7)) << 3) | (c & 7);
}

// s_nop 1 prologue: VALU-write -> MFMA-read hazard guard (inline asm bypasses
// the compiler's hazard recognizer).
static __device__ __forceinline__ f32x4 mfma16(short8 a, short8 b, f32x4 c) {
    asm volatile("s_nop 1\n\tv_mfma_f32_16x16x32_bf16 %0, %1, %2, %0"
                 : "+v"(c) : "v"(a), "v"(b));
    return c;
}
static __device__ __forceinline__ f32x4 mfma16k16(short4b a, short4b b, f32x4 c) {
    asm volatile("s_nop 1\n\tv_mfma_f32_16x16x16_bf16 %0, %1, %2, %0"
                 : "+v"(c) : "v"(a), "v"(b));
    return c;
}
// MFMA-write -> VALU-read guard
static __device__ __forceinline__ void fence4(f32x4* a) {
    asm volatile("s_nop 7\n\ts_nop 7\n\ts_nop 7"
                 : "+v"(a[0]), "+v"(a[1]), "+v"(a[2]), "+v"(a[3]));
}
static __device__ __forceinline__ void fence6(f32x4* a) {
    asm volatile("s_nop 7\n\ts_nop 7\n\ts_nop 7"
                 : "+v"(a[0]), "+v"(a[1]), "+v"(a[2]), "+v"(a[3]), "+v"(a[4]), "+v"(a[5]));
}

// Wave computes C[rbase..rbase+15][0..NT*16) over K=64.
// Ab: bf16 [rows][64] swizzled (8-granule); Bb: same (rows = output cols).
// Self-consistent k-slot packing: sigma(hi,g,j) = (g+hi)*8+j for both operands.
template<int NT>
static __device__ __forceinline__ void gemm64(const u16* Ab, const u16* Bb,
                                              int lane, int rbase, f32x4* acc) {
    const int r15 = lane & 15, hi = lane >> 4;
    const int arow = rbase + r15;
    const short8 a0 = *(const short8*)(Ab + arow * 64 + (((0 + hi) ^ (arow & 7)) << 3));
    const short8 a1 = *(const short8*)(Ab + arow * 64 + (((4 + hi) ^ (arow & 7)) << 3));
    #pragma unroll
    for (int nt = 0; nt < NT; ++nt) {
        const int brow = nt * 16 + r15;
        const short8 b0 = *(const short8*)(Bb + brow * 64 + (((0 + hi) ^ (brow & 7)) << 3));
        const short8 b1 = *(const short8*)(Bb + brow * 64 + (((4 + hi) ^ (brow & 7)) << 3));
        acc[nt] = mfma16(a0, b0, acc[nt]);
        acc[nt] = mfma16(a1, b1, acc[nt]);
    }
}

// ---------------- weight prep: f32 -> bf16 swizzled LDS images in ws ----------------
extern "C" __global__ void __launch_bounds__(256)
slm_prep(const void* __restrict__ g_wq, const void* __restrict__ g_wk,
         const void* __restrict__ g_wv, const void* __restrict__ g_wo,
         const void* __restrict__ g_w1, const void* __restrict__ g_w2,
         const void* __restrict__ g_lmw, const void* __restrict__ g_ln1g,
         u16* __restrict__ ws)
{
    const int tid = threadIdx.x, blk = blockIdx.x;
    const bool F32 = (((const unsigned int*)g_ln1g)[0] == 0x3F800000u);
    if (blk < 12) {                         // wq / wk / wv
        int m = blk >> 2, l = blk & 3;
        const void* src = (m == 0) ? g_wq : (m == 1) ? g_wk : g_wv;
        u16* dst = ws + (m == 0 ? WS_WQ : m == 1 ? WS_WK : WS_WV) + l * 4096;
        for (int i = tid; i < 1024; i += 256) {
            int s4 = i & 3, c = (i >> 2) & 63, h = i >> 8;
            float4 w4 = ldf4(src, l * 4096 + h * 1024 + c * 16 + s4 * 4, F32);
            int nb = h * 16 + s4 * 4;
            dst[(nb + 0) * 64 + swzi(nb + 0, c)] = f2bf(w4.x);
            dst[(nb + 1) * 64 + swzi(nb + 1, c)] = f2bf(w4.y);
            dst[(nb + 2) * 64 + swzi(nb + 2, c)] = f2bf(w4.z);
            dst[(nb + 3) * 64 + swzi(nb + 3, c)] = f2bf(w4.w);
        }
    } else if (blk < 16) {                  // wo
        int l = blk - 12;
        u16* dst = ws + WS_WO + l * 4096;
        for (int q = tid; q < 1024; q += 256) {
            int n4 = (q & 15) * 4, c = q >> 4;
            float4 w4 = ldf4(g_wo, l * 4096 + c * 64 + n4, F32);
            dst[(n4 + 0) * 64 + swzi(n4 + 0, c)] = f2bf(w4.x);
            dst[(n4 + 1) * 64 + swzi(n4 + 1, c)] = f2bf(w4.y);
            dst[(n4 + 2) * 64 + swzi(n4 + 2, c)] = f2bf(w4.z);
            dst[(n4 + 3) * 64 + swzi(n4 + 3, c)] = f2bf(w4.w);
        }
    } else if (blk < 32) {                  // w1 chunks
        int t2 = blk - 16, l = t2 >> 2, ch = t2 & 3;
        u16* dst = ws + WS_W1 + t2 * 4096;
        for (int q = tid; q < 1024; q += 256) {
            int j4 = (q & 15) * 4, c = q >> 4;
            float4 w4 = ldf4(g_w1, l * 16384 + c * 256 + ch * 64 + j4, F32);
            dst[(j4 + 0) * 64 + swzi(j4 + 0, c)] = f2bf(w4.x);
            dst[(j4 + 1) * 64 + swzi(j4 + 1, c)] = f2bf(w4.y);
            dst[(j4 + 2) * 64 + swzi(j4 + 2, c)] = f2bf(w4.z);
            dst[(j4 + 3) * 64 + swzi(j4 + 3, c)] = f2bf(w4.w);
        }
    } else if (blk < 48) {                  // w2 chunks
        int t2 = blk - 32, l = t2 >> 2, ch = t2 & 3;
        u16* dst = ws + WS_W2 + t2 * 4096;
        for (int q = tid; q < 1024; q += 256) {
            int n4 = (q & 15) * 4, jj = q >> 4;
            float4 w4 = ldf4(g_w2, l * 16384 + (ch * 64 + jj) * 64 + n4, F32);
            dst[(n4 + 0) * 64 + swzi(n4 + 0, jj)] = f2bf(w4.x);
            dst[(n4 + 1) * 64 + swzi(n4 + 1, jj)] = f2bf(w4.y);
            dst[(n4 + 2) * 64 + swzi(n4 + 2, jj)] = f2bf(w4.z);
            dst[(n4 + 3) * 64 + swzi(n4 + 3, jj)] = f2bf(w4.w);
        }
    } else {                                // lm_w
        u16* dst = ws + WS_LMW;
        for (int q = tid; q < 1536; q += 256) {
            int v4 = (q % 24) * 4, c = q / 24;
            float4 w4 = ldf4(g_lmw, c * 96 + v4, F32);
            dst[(v4 + 0) * 64 + swzi(v4 + 0, c)] = f2bf(w4.x);
            dst[(v4 + 1) * 64 + swzi(v4 + 1, c)] = f2bf(w4.y);
            dst[(v4 + 2) * 64 + swzi(v4 + 2, c)] = f2bf(w4.z);
            dst[(v4 + 3) * 64 + swzi(v4 + 3, c)] = f2bf(w4.w);
        }
    }
}

// ---------------- main: one block per sequence, 4 waves ----------------
extern "C" __global__ void __launch_bounds__(256, 2)
slm_fwd(const int* __restrict__ g_idx, const int* __restrict__ g_tgt,
        const void* __restrict__ g_tok, const void* __restrict__ g_pos,
        const void* __restrict__ g_ln1g, const void* __restrict__ g_ln1b,
        const void* __restrict__ g_bo,
        const void* __restrict__ g_ln2g, const void* __restrict__ g_ln2b,
        const void* __restrict__ g_b1, const void* __restrict__ g_b2,
        const void* __restrict__ g_lnfg, const void* __restrict__ g_lnfb,
        const void* __restrict__ g_lmb,
        const u16* __restrict__ ws,
        float* __restrict__ g_out, float* g_loss)
{
    // LDS pool (byte offsets, all 16B aligned)
    __shared__ __align__(16) char pool[74304];
    u16*   xs  = (u16*)(pool);              // [64][68] residual bf16        (8704 B)
    u16*   hb  = (u16*)(pool + 8704);       // [64][64] swz, LN/attn out     (8192 B)
    u16*   w0  = (u16*)(pool + 16896);      // weight slot                   (8192 B)
    u16*   w1s = (u16*)(pool + 25088);      // weight slot                   (8192 B)
    u16*   w2s = (u16*)(pool + 33280);      // weight slot                   (8192 B)
    u16*   qh  = (u16*)(pool + 41472);      // [4][64][16] Q / MLP-hid / lw  (8192 B)
    u16*   kh  = (u16*)(pool + 49664);      // [4][64][16] K                 (8192 B)
    u16*   vt  = (u16*)(pool + 57856);      // [4][16][64] V^T swz           (8192 B)
    u16*   Pb  = (u16*)(pool + 66048);      // [4][16][64] P swz             (8192 B)
    float* redl= (float*)(pool + 74240);    // [16]
    u16*   hid = qh;                        // MLP hidden aliases qh
    u16*   lw  = qh;                        // lm-head weight aliases qh..kh (12KB)

    const int tid  = threadIdx.x;
    const int wid  = tid >> 6;
    const int lane = tid & 63;
    const int hi   = lane >> 4;
    const int r15  = lane & 15;
    const int bIdx = blockIdx.x;
    const int rb   = wid * 16;
    const f32x4 zero4 = {0.f, 0.f, 0.f, 0.f};

    const bool F32 = (((const unsigned int*)g_ln1g)[0] == 0x3F800000u);

    auto cp8k = [&](u16* dst, const u16* src) {     // 8KB image copy, 256 thr
        const uint4* s = (const uint4*)src; uint4* d = (uint4*)dst;
        d[tid] = s[tid]; d[tid + 256] = s[tid + 256];
    };

    // ---------------- embedding ----------------
    for (int t = wid; t < 64; t += 4) {
        int tok = g_idx[bIdx * 64 + t];
        float e = ldf(g_tok, tok * 64 + lane, F32) + ldf(g_pos, t * 64 + lane, F32);
        xs[t * 68 + lane] = f2bf(e);
    }
    __syncthreads();

    // LayerNorm xs -> hb (swizzled); 4 threads per token
    auto ln_phase = [&](const void* gp, const void* bp, int off) {
        int q4 = tid & 3, tk = tid >> 2;
        float xv[16]; float s1 = 0.f, s2 = 0.f;
        #pragma unroll
        for (int i = 0; i < 16; ++i) {
            float f = bf2f(xs[tk * 68 + q4 * 16 + i]);
            xv[i] = f; s1 += f; s2 += f * f;
        }
        s1 += __shfl_xor(s1, 1); s1 += __shfl_xor(s1, 2);
        s2 += __shfl_xor(s2, 1); s2 += __shfl_xor(s2, 2);
        float m  = s1 * 0.015625f;
        float rs = rsqrtf(s2 * 0.015625f - m * m + 1e-5f);
        unsigned w[8];
        #pragma unroll
        for (int i = 0; i < 16; i += 2) {
            int c0 = q4 * 16 + i;
            float y0 = (xv[i] - m) * rs * ldf(gp, off + c0, F32)       + ldf(bp, off + c0, F32);
            float y1 = (xv[i+1] - m) * rs * ldf(gp, off + c0 + 1, F32) + ldf(bp, off + c0 + 1, F32);
            w[i >> 1] = (unsigned)f2bf(y0) | ((unsigned)f2bf(y1) << 16);
        }
        int g0 = (2 * q4) ^ (tk & 7), g1 = (2 * q4 + 1) ^ (tk & 7);
        *(uint4*)&hb[tk * 64 + (g0 << 3)] = make_uint4(w[0], w[1], w[2], w[3]);
        *(uint4*)&hb[tk * 64 + (g1 << 3)] = make_uint4(w[4], w[5], w[6], w[7]);
    };

    for (int l = 0; l < 4; ++l) {
        // ---- LN1 + stage QKV weight images ----
        ln_phase(g_ln1g, g_ln1b, l * 64);
        cp8k(w0,  ws + WS_WQ + l * 4096);
        cp8k(w1s, ws + WS_WK + l * 4096);
        cp8k(w2s, ws + WS_WV + l * 4096);
        __syncthreads();                                    // B1

        // ---- QKV MFMA ----
        f32x4 aq[4], ak[4], av[4];
        #pragma unroll
        for (int nt = 0; nt < 4; ++nt) { aq[nt] = zero4; ak[nt] = zero4; av[nt] = zero4; }
        gemm64<4>(hb, w0,  lane, rb, aq);
        gemm64<4>(hb, w1s, lane, rb, ak);
        gemm64<4>(hb, w2s, lane, rb, av);
        fence4(aq); fence4(ak); fence4(av);
        __syncthreads();                                    // B2

        // ---- epilogue: Q->qh, K->kh (K16 4-granule layout), V->vt (transposed);
        //      stage wo image into w0 ----
        #pragma unroll
        for (int nt = 0; nt < 4; ++nt) {
            #pragma unroll
            for (int r = 0; r < 4; ++r) {
                int t = rb + hi * 4 + r;                    // token
                int g4 = ((r15 >> 2) ^ r ^ hi) << 2;        // (s>>2) ^ (t&3) ^ ((t>>2)&3)
                qh[nt * 1024 + t * 16 + g4 + (r15 & 3)] = f2bf(aq[nt][r]);
                kh[nt * 1024 + t * 16 + g4 + (r15 & 3)] = f2bf(ak[nt][r]);
                vt[nt * 1024 + r15 * 64 + swzi(r15, t)] = f2bf(av[nt][r]);
            }
        }
        cp8k(w0, ws + WS_WO + l * 4096);
        __syncthreads();                                    // B3

        // ---- attention (wave = head wid), fully MFMA ----
        {
            const u16* qhh = qh + wid * 1024;
            const u16* khh = kh + wid * 1024;
            const u16* vth = vt + wid * 1024;
            u16*       phh = Pb + wid * 1024;
            f32x4 oacc[4]; float dd[4][4];
            #pragma unroll
            for (int ti = 0; ti < 4; ++ti) oacc[ti] = zero4;
            #pragma unroll
            for (int ti = 0; ti < 4; ++ti) {
                const int tA = ti * 16 + r15;
                short4b aQ = *(const short4b*)(qhh + tA * 16 +
                              ((hi ^ (tA & 3) ^ ((tA >> 2) & 3)) << 2));
                f32x4 sc[4];
                #pragma unroll
                for (int tj = 0; tj < 4; ++tj) {
                    const int uB = tj * 16 + r15;
                    short4b bK = *(const short4b*)(khh + uB * 16 +
                                  ((hi ^ (uB & 3) ^ ((uB >> 2) & 3)) << 2));
                    sc[tj] = mfma16k16(aQ, bK, zero4);
                }
                fence4(sc);
                float den[4] = {0.f, 0.f, 0.f, 0.f};
                #pragma unroll
                for (int tj = 0; tj < 4; ++tj) {
                    #pragma unroll
                    for (int r = 0; r < 4; ++r) {
                        int tq = ti * 16 + hi * 4 + r, uu = tj * 16 + r15;
                        float p = (uu <= tq) ? __expf(fminf(sc[tj][r] * 0.25f, 50.f)) : 0.f;
                        den[r] += p;
                        int rl = hi * 4 + r;
                        phh[rl * 64 + swzi(rl, uu)] = f2bf(p);
                    }
                }
                #pragma unroll
                for (int r = 0; r < 4; ++r) {
                    float d = den[r];
                    d += __shfl_xor(d, 1); d += __shfl_xor(d, 2);
                    d += __shfl_xor(d, 4); d += __shfl_xor(d, 8);
                    dd[ti][r] = d;
                }
                // PV for this ti (intra-wave LDS round-trip; compiler orders ds ops)
                short8 pa0 = *(const short8*)(phh + r15 * 64 + (((0 + hi) ^ (r15 & 7)) << 3));
                short8 pa1 = *(const short8*)(phh + r15 * 64 + (((4 + hi) ^ (r15 & 7)) << 3));
                short8 vb0 = *(const short8*)(vth + r15 * 64 + (((0 + hi) ^ (r15 & 7)) << 3));
                short8 vb1 = *(const short8*)(vth + r15 * 64 + (((4 + hi) ^ (r15 & 7)) << 3));
                oacc[ti] = mfma16(pa0, vb0, oacc[ti]);
                oacc[ti] = mfma16(pa1, vb1, oacc[ti]);
            }
            fence4(oacc);
            #pragma unroll
            for (int ti = 0; ti < 4; ++ti) {
                #pragma unroll
                for (int r = 0; r < 4; ++r) {
                    int t = ti * 16 + hi * 4 + r;
                    int col = wid * 16 + r15;
                    float inv = __builtin_amdgcn_rcpf(dd[ti][r]);
                    hb[t * 64 + swzi(t, col)] = f2bf(oacc[ti][r] * inv);
                }
            }
        }
        __syncthreads();                                    // B4

        // ---- output projection + residual ----
        {
            f32x4 ap[4];
            #pragma unroll
            for (int nt = 0; nt < 4; ++nt) ap[nt] = zero4;
            gemm64<4>(hb, w0, lane, rb, ap);
            fence4(ap);
            #pragma unroll
            for (int nt = 0; nt < 4; ++nt) {
                int col = nt * 16 + r15;
                float bb = ldf(g_bo, l * 64 + col, F32);
                #pragma unroll
                for (int r = 0; r < 4; ++r) {
                    int row = rb + hi * 4 + r;
                    xs[row * 68 + col] = f2bf(bf2f(xs[row * 68 + col]) + ap[nt][r] + bb);
                }
            }
        }
        __syncthreads();                                    // B5

        // ---- LN2 + MLP ----
        ln_phase(g_ln2g, g_ln2b, l * 64);
        cp8k(w1s, ws + WS_W1 + (l * 4 + 0) * 4096);
        cp8k(w2s, ws + WS_W2 + (l * 4 + 0) * 4096);
        __syncthreads();                                    // B6
        f32x4 acc2[4];
        #pragma unroll
        for (int nt = 0; nt < 4; ++nt) acc2[nt] = zero4;
        for (int ch = 0; ch < 4; ++ch) {
            f32x4 hacc[4];
            #pragma unroll
            for (int nt = 0; nt < 4; ++nt) hacc[nt] = zero4;
            gemm64<4>(hb, w1s, lane, rb, hacc);
            fence4(hacc);
            #pragma unroll
            for (int nt = 0; nt < 4; ++nt) {
                int col = nt * 16 + r15;
                float bb = ldf(g_b1, l * 256 + ch * 64 + col, F32);
                #pragma unroll
                for (int r = 0; r < 4; ++r) {
                    int row = rb + hi * 4 + r;
                    hid[row * 64 + swzi(row, col)] = f2bf(fmaxf(hacc[nt][r] + bb, 0.f));
                }
            }
            __syncthreads();                                // B7: hid ready, w1s reads done
            gemm64<4>(hid, w2s, lane, rb, acc2);
            if (ch < 3) cp8k(w1s, ws + WS_W1 + (l * 4 + ch + 1) * 4096);  // overlaps accgemm
            __syncthreads();                                // B8: w2s reads done
            if (ch < 3) cp8k(w2s, ws + WS_W2 + (l * 4 + ch + 1) * 4096);
        }
        fence4(acc2);
        #pragma unroll
        for (int nt = 0; nt < 4; ++nt) {
            int col = nt * 16 + r15;
            float bb = ldf(g_b2, l * 64 + col, F32);
            #pragma unroll
            for (int r = 0; r < 4; ++r) {
                int row = rb + hi * 4 + r;
                xs[row * 68 + col] = f2bf(bf2f(xs[row * 68 + col]) + acc2[nt][r] + bb);
            }
        }
        __syncthreads();                                    // B9 (layer end)
    }

    // ---------------- final LN + lm head + loss ----------------
    ln_phase(g_lnfg, g_lnfb, 0);
    {   // stage lm_w image (12KB) into lw (aliases qh+kh, both dead)
        const uint4* s = (const uint4*)(ws + WS_LMW); uint4* d = (uint4*)lw;
        d[tid] = s[tid]; d[tid + 256] = s[tid + 256]; d[tid + 512] = s[tid + 512];
    }
    __syncthreads();

    f32x4 la[6];
    #pragma unroll
    for (int nt = 0; nt < 6; ++nt) la[nt] = zero4;
    gemm64<6>(hb, lw, lane, rb, la);
    fence6(la);
    #pragma unroll
    for (int nt = 0; nt < 6; ++nt) {
        float bb = ldf(g_lmb, nt * 16 + r15, F32);
        #pragma unroll
        for (int r = 0; r < 4; ++r) la[nt][r] += bb;
    }

    float lsum = 0.f;
    #pragma unroll
    for (int r = 0; r < 4; ++r) {
        int row = rb + hi * 4 + r;
        float mx = la[0][r];
        #pragma unroll
        for (int nt = 1; nt < 6; ++nt) mx = fmaxf(mx, la[nt][r]);
        mx = fmaxf(mx, __shfl_xor(mx, 1));
        mx = fmaxf(mx, __shfl_xor(mx, 2));
        mx = fmaxf(mx, __shfl_xor(mx, 4));
        mx = fmaxf(mx, __shfl_xor(mx, 8));
        float ps = 0.f;
        #pragma unroll
        for (int nt = 0; nt < 6; ++nt) ps += __expf(la[nt][r] - mx);
        ps += __shfl_xor(ps, 1); ps += __shfl_xor(ps, 2);
        ps += __shfl_xor(ps, 4); ps += __shfl_xor(ps, 8);
        size_t base = (size_t)(bIdx * 64 + row) * 96;
        #pragma unroll
        for (int nt = 0; nt < 6; ++nt) g_out[base + nt * 16 + r15] = la[nt][r];
        int tg = g_tgt[bIdx * 64 + row];
        float contrib = 0.f;
        #pragma unroll
        for (int nt = 0; nt < 6; ++nt)
            contrib += (((tg >> 4) == nt) && ((tg & 15) == r15)) ? la[nt][r] : 0.f;
        contrib += __shfl_xor(contrib, 1); contrib += __shfl_xor(contrib, 2);
        contrib += __shfl_xor(contrib, 4); contrib += __shfl_xor(contrib, 8);
        lsum += (mx + logf(ps) - contrib);
    }
    if (r15 == 0) redl[wid * 4 + hi] = lsum;
    __syncthreads();
    if (tid == 0 && g_loss) {
        float t = 0.f;
        #pragma unroll
        for (int i = 0; i < 16; ++i) t += redl[i];
        atomicAdd(g_loss, t * (1.0f / 262144.0f));
    }
}

extern "C" void kernel_launch(void* const* d_in, const int* in_sizes, int n_in,
                              void* d_out, int out_size, void* d_ws, size_t ws_size,
                              hipStream_t stream) {
    (void)in_sizes; (void)n_in; (void)ws_size;
    float* out = (float*)d_out;
    float* loss_ptr = nullptr;
    if (out_size > LOGITS_N) {
        loss_ptr = out + LOGITS_N;
        hipMemsetAsync(loss_ptr, 0, sizeof(float) * (size_t)(out_size - LOGITS_N), stream);
    }
    u16* ws = (u16*)d_ws;
    slm_prep<<<dim3(49), dim3(256), 0, stream>>>(
        d_in[6], d_in[7], d_in[8], d_in[9],     // wq wk wv wo
        d_in[13], d_in[15], d_in[19],           // w1 w2 lmw
        d_in[4],                                // ln1_g (dtype sniff)
        ws);
    slm_fwd<<<dim3(4096), dim3(256), 0, stream>>>(
        (const int*)d_in[0], (const int*)d_in[1],
        d_in[2], d_in[3],                       // tok_emb pos_emb
        d_in[4], d_in[5],                       // ln1 g/b
        d_in[10],                               // bo
        d_in[11], d_in[12],                     // ln2 g/b
        d_in[14], d_in[16],                     // b1 b2
        d_in[17], d_in[18],                     // lnf g/b
        d_in[20],                               // lm_b
        ws, out, loss_ptr);
}